// Round 7
// baseline (97.626 us; speedup 1.0000x reference)
//
#include <hip/hip_runtime.h>

#define TOPK_K 13
#define KPAD 16
#define CAP 416          // >= max in-box anchors per gt (<=395 for 128px box)
#define NA_C 8400
#define RTHREADS 1024

// ---- shared math helpers: every am/IoU value in all kernels flows through
// these, so threshold comparisons and argmax are bit-exact vs each other. ----

__device__ __forceinline__ float iou_clip(const float4 g, const float4 p) {
    float ix1 = fmaxf(g.x, p.x), iy1 = fmaxf(g.y, p.y);
    float ix2 = fminf(g.z, p.z), iy2 = fminf(g.w, p.w);
    float iw = fmaxf(ix2 - ix1, 0.f);
    float ih = fmaxf(iy2 - iy1, 0.f);
    float inter = iw * ih;
    float a1 = (g.z - g.x) * (g.w - g.y);
    float a2 = (p.z - p.x) * (p.w - p.y);
    float iou = inter / (a1 + a2 - inter + 1e-7f);
    return fmaxf(iou, 0.f);
}

__device__ __forceinline__ float in_box(float ax, float ay, const float4 g) {
    float m = fminf(fminf(ax - g.x, ay - g.y), fminf(g.z - ax, g.w - ay));
    return (m > 0.f) ? 1.f : 0.f;
}

__device__ __forceinline__ float align_metric_f(float sqs, float iou, float valid) {
    float p2 = iou * iou;
    float p6 = p2 * p2 * p2;
    return sqs * p6 * valid;
}

// anchor index -> center coords (bit-exact vs reference (arange+0.5)*s)
__device__ __forceinline__ void anc_xy(int i, float& ax, float& ay) {
    int lvl = (i < 6400) ? 0 : (i < 8000 ? 1 : 2);
    int n   = (lvl == 0) ? 80 : (lvl == 1 ? 40 : 20);
    int off = (lvl == 0) ? 0  : (lvl == 1 ? 6400 : 8000);
    float sf = (float)(8 << lvl);
    int r = i - off;
    int iy = r / n, ix = r - iy * n;
    ax = (ix + 0.5f) * sf;
    ay = (iy + 0.5f) * sf;
}

// ---- Kernel 1: per-(b,g) wave. Top-13 threshold over the analytic anchor
// rectangle, then ballot-compacted claim list (no atomics, no init needed). ----
__global__ __launch_bounds__(256) void k_gt(
    const float* __restrict__ pd_scores, const float* __restrict__ pd_bboxes,
    const float* __restrict__ gt_bboxes, const float* __restrict__ mask_gt,
    int* __restrict__ claims, int* __restrict__ nclaim,
    int B, int G, int NA)
{
    int w = blockIdx.x * (blockDim.x >> 6) + (threadIdx.x >> 6);
    int lane = threadIdx.x & 63;
    if (w >= B * G) return;
    if (mask_gt[w] == 0.f) { if (lane == 0) nclaim[w] = 0; return; }
    int b = w / G;
    float4 gb = *(const float4*)(gt_bboxes + (size_t)w * 4);
    const float* ps = pd_scores + (size_t)b * NA;
    const float* pb = pd_bboxes + (size_t)b * NA * 4;

    // analytic candidate rectangle per stride level
    int rix0[3], riy0[3], rix1[3], riy1[3];
    #pragma unroll
    for (int lvl = 0; lvl < 3; ++lvl) {
        const int n = (lvl == 0) ? 80 : (lvl == 1 ? 40 : 20);
        const float sf = (float)(8 << lvl);
        rix0[lvl] = max(0,     (int)floorf(gb.x / sf - 0.5f));
        riy0[lvl] = max(0,     (int)floorf(gb.y / sf - 0.5f));
        rix1[lvl] = min(n - 1, (int)ceilf (gb.z / sf - 0.5f));
        riy1[lvl] = min(n - 1, (int)ceilf (gb.w / sf - 0.5f));
    }

    // pass 1: per-lane top-KPAD (descending, all static indices)
    float t[KPAD];
    #pragma unroll
    for (int i = 0; i < KPAD; ++i) t[i] = 0.f;

    #pragma unroll
    for (int lvl = 0; lvl < 3; ++lvl) {
        const int n   = (lvl == 0) ? 80 : (lvl == 1 ? 40 : 20);
        const int off = (lvl == 0) ? 0  : (lvl == 1 ? 6400 : 8000);
        const float sf = (float)(8 << lvl);
        int wdt = rix1[lvl] - rix0[lvl] + 1, hgt = riy1[lvl] - riy0[lvl] + 1;
        if (wdt <= 0 || hgt <= 0) continue;
        int n_c = wdt * hgt;
        for (int c = lane; c < n_c; c += 64) {
            int ix = rix0[lvl] + (c % wdt);
            int iy = riy0[lvl] + (c / wdt);
            float ax = (ix + 0.5f) * sf;
            float ay = (iy + 0.5f) * sf;
            if (in_box(ax, ay, gb) != 0.f) {
                int a = off + iy * n + ix;
                float4 p = *(const float4*)(pb + (size_t)a * 4);
                float iou = iou_clip(gb, p);
                float sqs = sqrtf(fmaxf(ps[a], 0.f));
                float am = align_metric_f(sqs, iou, 1.f);
                if (am > t[KPAD - 1]) {
                    t[KPAD - 1] = am;
                    #pragma unroll
                    for (int i = KPAD - 1; i > 0; --i) {
                        float hi = fmaxf(t[i - 1], t[i]);
                        float lo = fminf(t[i - 1], t[i]);
                        t[i - 1] = hi; t[i] = lo;
                    }
                }
            }
        }
    }

    // butterfly all-reduce merge: all lanes end with the global top-KPAD
    for (int off = 1; off < 64; off <<= 1) {
        float o[KPAD], m[KPAD];
        #pragma unroll
        for (int i = 0; i < KPAD; ++i) o[i] = __shfl_xor(t[i], off, 64);
        #pragma unroll
        for (int i = 0; i < KPAD; ++i) m[i] = fmaxf(t[i], o[KPAD - 1 - i]);
        #pragma unroll
        for (int s = 8; s >= 1; s >>= 1) {
            #pragma unroll
            for (int i = 0; i < KPAD; ++i) {
                if ((i & s) == 0) {
                    float hi = fmaxf(m[i], m[i + s]);
                    float lo = fminf(m[i], m[i + s]);
                    m[i] = hi; m[i + s] = lo;
                }
            }
        }
        #pragma unroll
        for (int i = 0; i < KPAD; ++i) t[i] = m[i];
    }
    float thr = t[TOPK_K - 1];

    // pass 2: ballot-compacted claim list (wave-uniform loop!)
    int* listw = claims + (size_t)w * CAP;
    int base = 0;
    #pragma unroll
    for (int lvl = 0; lvl < 3; ++lvl) {
        const int n   = (lvl == 0) ? 80 : (lvl == 1 ? 40 : 20);
        const int off = (lvl == 0) ? 0  : (lvl == 1 ? 6400 : 8000);
        const float sf = (float)(8 << lvl);
        int wdt = rix1[lvl] - rix0[lvl] + 1, hgt = riy1[lvl] - riy0[lvl] + 1;
        if (wdt <= 0 || hgt <= 0) continue;
        int n_c = wdt * hgt;
        for (int c0 = 0; c0 < n_c; c0 += 64) {
            int c = c0 + lane;
            bool pass = false;
            int a = 0;
            if (c < n_c) {
                int ix = rix0[lvl] + (c % wdt);
                int iy = riy0[lvl] + (c / wdt);
                float ax = (ix + 0.5f) * sf;
                float ay = (iy + 0.5f) * sf;
                if (in_box(ax, ay, gb) != 0.f) {
                    a = off + iy * n + ix;
                    float4 p = *(const float4*)(pb + (size_t)a * 4);
                    float iou = iou_clip(gb, p);
                    float sqs = sqrtf(fmaxf(ps[a], 0.f));
                    float am = align_metric_f(sqs, iou, 1.f);
                    pass = (am >= thr);
                }
            }
            unsigned long long bal = __ballot(pass);
            if (pass) {
                int idx = base + (int)__popcll(bal & ((1ull << lane) - 1ull));
                listw[idx] = a;
            }
            base += (int)__popcll(bal);
        }
    }
    if (lane == 0) nclaim[w] = base;
}

// ---- Kernel 2: one block per batch. LDS claim-count build -> resolve ->
// pam/pim in LDS -> normalized scores. All outputs written here. ----
__global__ __launch_bounds__(RTHREADS) void k_rest(
    const float* __restrict__ pd_scores, const float* __restrict__ pd_bboxes,
    const int* __restrict__ gt_labels, const float* __restrict__ gt_bboxes,
    const float* __restrict__ mask_gt,
    const int* __restrict__ claims, const int* __restrict__ nclaim,
    float* __restrict__ out_labels, float* __restrict__ out_bboxes,
    float* __restrict__ out_scores, float* __restrict__ out_fg,
    int G, int NA)
{
    __shared__ int    sclaim[NA_C];   // phase B: (count<<20)+sum_g; phase C+: tgt | (fg<<8)
    __shared__ float4 sbox[64];
    __shared__ float  smask[64];
    __shared__ int    slab[64];
    __shared__ int    spam[64];
    __shared__ int    spim[64];

    const int b   = blockIdx.x;
    const int tid = threadIdx.x;
    const int lane = tid & 63;

    // ---- phase A: init LDS ----
    for (int i = tid; i < NA; i += RTHREADS) sclaim[i] = 0;
    if (tid < 64) {
        sbox[tid]  = *(const float4*)(gt_bboxes + ((size_t)b * G + tid) * 4);
        smask[tid] = mask_gt[b * G + tid];
        int l = gt_labels[b * G + tid];
        slab[tid]  = (l < 0) ? 0 : l;
        spam[tid]  = 0;
        spim[tid]  = 0;
    }
    __syncthreads();

    // ---- phase B: scatter claim lists into packed per-anchor words ----
    {
        int wid = tid >> 6;
        for (int g = wid; g < G; g += (RTHREADS >> 6)) {
            int w = b * G + g;
            int len = nclaim[w];
            const int* lw = claims + (size_t)w * CAP;
            int add = (1 << 20) + g;
            for (int j = lane; j < len; j += 64)
                atomicAdd(&sclaim[lw[j]], add);
        }
    }
    __syncthreads();

    const float4 gl = sbox[lane];          // this lane's gt box (for disputes)
    const float* ps = pd_scores + (size_t)b * NA;
    const float* pb = pd_bboxes + (size_t)b * NA * 4;

    // ---- phase C: per-anchor resolve + primary outputs + pam/pim ----
    for (int i0 = 0; i0 < NA; i0 += RTHREADS) {
        int i = i0 + tid;
        bool act = (i < NA);
        int v = act ? sclaim[i] : 0;
        int c = v >> 20;
        float4 p = act ? *(const float4*)(pb + (size_t)i * 4)
                       : make_float4(0.f, 0.f, 0.f, 0.f);

        int tgt = (c == 1) ? (v & 0xFFFFF) : 0;

        // wave-cooperative disputed resolution (lane g = gt g, G == 64)
        unsigned long long dm = __ballot(c > 1);
        while (dm) {
            int l = __ffsll((long long)dm) - 1;
            dm &= dm - 1;
            float4 pl;
            pl.x = __shfl(p.x, l, 64); pl.y = __shfl(p.y, l, 64);
            pl.z = __shfl(p.z, l, 64); pl.w = __shfl(p.w, l, 64);
            float iou = iou_clip(gl, pl);
            int g = lane;
            #pragma unroll
            for (int off = 32; off >= 1; off >>= 1) {
                float oi = __shfl_xor(iou, off, 64);
                int   og = __shfl_xor(g,   off, 64);
                if (oi > iou || (oi == iou && og < g)) { iou = oi; g = og; }
            }
            if (lane == l) tgt = g;
        }

        if (act) {
            float4 gbt = sbox[tgt];
            float ax, ay; anc_xy(i, ax, ay);
            float sqs = sqrtf(fmaxf(ps[i], 0.f));
            float vt  = in_box(ax, ay, gbt) * smask[tgt];
            float iout = iou_clip(gbt, p);
            float amt = align_metric_f(sqs, iout, vt);
            bool fg = (c != 0);
            float amv = fg ? amt : 0.f;    // am * mask_pos (valid included)
            float iov = fg ? iout : 0.f;   // overlaps * mask_pos (no valid mult)

            size_t o = (size_t)b * NA + i;
            out_labels[o] = (float)slab[tgt];
            *(float4*)(out_bboxes + o * 4) = gbt;
            out_fg[o] = fg ? 1.f : 0.f;
            sclaim[i] = tgt | (fg ? 256 : 0);
            if (fg) {
                atomicMax(&spam[tgt], __float_as_int(amv));  // vals>=0: int order == float order
                atomicMax(&spim[tgt], __float_as_int(iov));
            }
        }
    }
    __syncthreads();

    // ---- phase E: normalized target scores (recompute amv bit-identically) ----
    for (int i = tid; i < NA; i += RTHREADS) {
        int v = sclaim[i];
        int tgt = v & 63;
        bool fg = (v & 256) != 0;
        float amv = 0.f;
        if (fg) {
            float4 gbt = sbox[tgt];
            float4 p = *(const float4*)(pb + (size_t)i * 4);
            float ax, ay; anc_xy(i, ax, ay);
            float sqs = sqrtf(fmaxf(ps[i], 0.f));
            float vt  = in_box(ax, ay, gbt) * smask[tgt];
            float iout = iou_clip(gbt, p);
            amv = align_metric_f(sqs, iout, vt);
        }
        float pa = __int_as_float(spam[tgt]);
        float pi = __int_as_float(spim[tgt]);
        float wgt = amv / (pa + 1e-9f) * pi;
        float onehot = (slab[tgt] == 0) ? 1.f : 0.f;   // NC==1
        out_scores[(size_t)b * NA + i] = onehot * wgt;
    }
}

extern "C" void kernel_launch(void* const* d_in, const int* in_sizes, int n_in,
                              void* d_out, int out_size, void* d_ws, size_t ws_size,
                              hipStream_t stream) {
    const float* pd_scores = (const float*)d_in[0];
    const float* pd_bboxes = (const float*)d_in[1];
    const int*   gt_labels = (const int*)d_in[3];
    const float* gt_bboxes = (const float*)d_in[4];
    const float* mask_gt   = (const float*)d_in[5];

    int NA = in_sizes[2] / 2;
    int B  = in_sizes[0] / NA;
    int G  = in_sizes[4] / (B * 4);

    float* out = (float*)d_out;
    float* out_labels = out;                               // (B,NA)
    float* out_bboxes = out_labels + (size_t)B * NA;       // (B,NA,4)
    float* out_scores = out_bboxes + (size_t)B * NA * 4;   // (B,NA,1)
    float* out_fg     = out_scores + (size_t)B * NA;       // (B,NA)

    int BG = B * G;
    int* claims = (int*)d_ws;                  // BG * CAP
    int* nclaim = claims + (size_t)BG * CAP;   // BG

    k_gt<<<dim3((BG + 3) / 4), dim3(256), 0, stream>>>(
        pd_scores, pd_bboxes, gt_bboxes, mask_gt, claims, nclaim, B, G, NA);

    k_rest<<<dim3(B), dim3(RTHREADS), 0, stream>>>(
        pd_scores, pd_bboxes, gt_labels, gt_bboxes, mask_gt, claims, nclaim,
        out_labels, out_bboxes, out_scores, out_fg, G, NA);
}

// Round 8
// 47.271 us; speedup vs baseline: 2.0652x; 2.0652x over previous
//
#include <hip/hip_runtime.h>

#define TOPK_K 13
#define KPAD 16
#define PCAP 384   // >= max in-box anchors per gt (<=336 for a 128px box)

// ---- shared math helpers: every am/IoU value in all kernels flows through
// these, so threshold comparisons and argmax are bit-exact vs each other. ----

__device__ __forceinline__ float iou_clip(const float4 g, const float4 p) {
    float ix1 = fmaxf(g.x, p.x), iy1 = fmaxf(g.y, p.y);
    float ix2 = fminf(g.z, p.z), iy2 = fminf(g.w, p.w);
    float iw = fmaxf(ix2 - ix1, 0.f);
    float ih = fmaxf(iy2 - iy1, 0.f);
    float inter = iw * ih;
    float a1 = (g.z - g.x) * (g.w - g.y);
    float a2 = (p.z - p.x) * (p.w - p.y);
    float iou = inter / (a1 + a2 - inter + 1e-7f);
    return fmaxf(iou, 0.f);
}

__device__ __forceinline__ float in_box(float ax, float ay, const float4 g) {
    float m = fminf(fminf(ax - g.x, ay - g.y), fminf(g.z - ax, g.w - ay));
    return (m > 0.f) ? 1.f : 0.f;
}

__device__ __forceinline__ float align_metric_f(float sqs, float iou, float valid) {
    float p2 = iou * iou;
    float p6 = p2 * p2 * p2;
    return sqs * p6 * valid;
}

// ---- Kernel 1: one wave per (b,g). Threshold = 13th-largest align metric.
// Fast path: if fewer than 13 POSITIVE metrics exist among in-box anchors,
// the 13th largest is 0 (reference pads with the zeros of the full 8400 row).
// Only npos>=13 (rare) runs the top-13 sort, over the compact positives list.
// Also zeroes pam/pim (saves an init node). ----
__global__ __launch_bounds__(256) void k_thresh(
    const float* __restrict__ pd_scores, const float* __restrict__ pd_bboxes,
    const float* __restrict__ gt_bboxes, const float* __restrict__ mask_gt,
    float* __restrict__ thr, int* __restrict__ pam, int* __restrict__ pim,
    int B, int G, int NA)
{
    __shared__ float plist[4][PCAP];
    __shared__ int   pcnt[4];

    int w4 = threadIdx.x >> 6;
    int lane = threadIdx.x & 63;
    int w = blockIdx.x * 4 + w4;
    bool wok = (w < B * G);
    bool valid = wok && (mask_gt[w] != 0.f);

    if (lane == 0) pcnt[w4] = 0;
    __syncthreads();

    if (valid) {
        int b = w / G;
        float4 gb = *(const float4*)(gt_bboxes + (size_t)w * 4);
        const float* ps = pd_scores + (size_t)b * NA;
        const float* pb = pd_bboxes + (size_t)b * NA * 4;

        // analytic candidate rectangle per stride level (anchors form a grid)
        #pragma unroll
        for (int lvl = 0; lvl < 3; ++lvl) {
            const int n   = (lvl == 0) ? 80 : (lvl == 1 ? 40 : 20);
            const int off = (lvl == 0) ? 0  : (lvl == 1 ? 6400 : 8000);
            const float sf = (float)(8 << lvl);
            int ix0 = max(0,     (int)floorf(gb.x / sf - 0.5f));
            int iy0 = max(0,     (int)floorf(gb.y / sf - 0.5f));
            int ix1 = min(n - 1, (int)ceilf (gb.z / sf - 0.5f));
            int iy1 = min(n - 1, (int)ceilf (gb.w / sf - 0.5f));
            int wdt = ix1 - ix0 + 1, hgt = iy1 - iy0 + 1;
            if (wdt <= 0 || hgt <= 0) continue;
            int n_c = wdt * hgt;
            for (int c = lane; c < n_c; c += 64) {
                int ix = ix0 + (c % wdt);
                int iy = iy0 + (c / wdt);
                float ax = (ix + 0.5f) * sf;   // exact f32 == reference anc
                float ay = (iy + 0.5f) * sf;
                if (in_box(ax, ay, gb) != 0.f) {
                    int a = off + iy * n + ix;
                    float4 p = *(const float4*)(pb + (size_t)a * 4);
                    float iou = iou_clip(gb, p);
                    float sqs = sqrtf(fmaxf(ps[a], 0.f));
                    float am = align_metric_f(sqs, iou, 1.f);
                    if (am > 0.f) {
                        int idx = atomicAdd(&pcnt[w4], 1);
                        if (idx < PCAP) plist[w4][idx] = am;
                    }
                }
            }
        }
    }
    __syncthreads();

    float thrv = 0.f;
    if (valid && pcnt[w4] >= TOPK_K) {
        // rare path: top-13 of the positives list (n <= 336)
        int n = pcnt[w4];
        float t[KPAD];
        #pragma unroll
        for (int i = 0; i < KPAD; ++i) t[i] = 0.f;
        for (int j = lane; j < n; j += 64) {
            float v = plist[w4][j];
            if (v > t[KPAD - 1]) {
                t[KPAD - 1] = v;
                #pragma unroll
                for (int i = KPAD - 1; i > 0; --i) {
                    float hi = fmaxf(t[i - 1], t[i]);
                    float lo = fminf(t[i - 1], t[i]);
                    t[i - 1] = hi; t[i] = lo;
                }
            }
        }
        // butterfly merge across 64 lanes (keep top-KPAD, descending)
        for (int off = 1; off < 64; off <<= 1) {
            float o[KPAD], m[KPAD];
            #pragma unroll
            for (int i = 0; i < KPAD; ++i) o[i] = __shfl_xor(t[i], off, 64);
            #pragma unroll
            for (int i = 0; i < KPAD; ++i) m[i] = fmaxf(t[i], o[KPAD - 1 - i]);
            #pragma unroll
            for (int s = 8; s >= 1; s >>= 1) {
                #pragma unroll
                for (int i = 0; i < KPAD; ++i) {
                    if ((i & s) == 0) {
                        float hi = fmaxf(m[i], m[i + s]);
                        float lo = fminf(m[i], m[i + s]);
                        m[i] = hi; m[i + s] = lo;
                    }
                }
            }
            #pragma unroll
            for (int i = 0; i < KPAD; ++i) t[i] = m[i];
        }
        thrv = t[TOPK_K - 1];
    }

    if (wok && lane == 0) {
        thr[w] = thrv;
        pam[w] = 0;    // zero the per-gt max accumulators here (no init node)
        pim[w] = 0;
    }
}

// ---- Kernel 2: per-(b,anchor) assignment. 64-gt loop with wave-level
// in-box gating (anchors in a wave are spatially contiguous, so ~1-2 of 64
// gts have any in-box lane); disputes resolved wave-cooperatively. ----
__global__ __launch_bounds__(256) void k_assign(
    const float* __restrict__ pd_scores, const float* __restrict__ pd_bboxes,
    const float* __restrict__ anc, const int* __restrict__ gt_labels,
    const float* __restrict__ gt_bboxes, const float* __restrict__ mask_gt,
    const float* __restrict__ thr,
    float* __restrict__ out_labels, float* __restrict__ out_bboxes,
    float* __restrict__ out_fg,
    int* __restrict__ ws_tgt, float* __restrict__ ws_amv,
    int* __restrict__ pam, int* __restrict__ pim,
    int B, int G, int NA)
{
    __shared__ float4 sbox[64];
    __shared__ float  smask[64];
    __shared__ float  sthr[64];
    __shared__ int    slab[64];

    int b = blockIdx.y;
    int tid = threadIdx.x;
    if (tid < 64) {
        sbox[tid]  = *(const float4*)(gt_bboxes + ((size_t)b * G + tid) * 4);
        smask[tid] = mask_gt[b * G + tid];
        sthr[tid]  = thr[b * G + tid];
        int l = gt_labels[b * G + tid];
        slab[tid]  = (l < 0) ? 0 : l;
    }
    __syncthreads();

    int a = blockIdx.x * blockDim.x + tid;
    bool act = (a < NA);                 // no early return: all lanes serve shfl
    int lane = tid & 63;
    int ac = act ? a : (NA - 1);
    size_t o = (size_t)b * NA + ac;

    float4 p = *(const float4*)(pd_bboxes + o * 4);
    float ax = anc[2 * ac], ay = anc[2 * ac + 1];
    float sqs = sqrtf(fmaxf(pd_scores[o], 0.f));

    int fg = 0, firstg = 0;
    for (int g = 0; g < 64; ++g) {
        float4 gbb = sbox[g];
        bool cand = act && (in_box(ax, ay, gbb) != 0.f) && (smask[g] != 0.f);
        if (__any(cand)) {
            float iou = iou_clip(gbb, p);
            float am = align_metric_f(sqs, iou, 1.f);
            bool pass = cand && (am >= sthr[g]);
            if (pass) { if (fg == 0) firstg = g; ++fg; }
        }
    }

    int tgt = (fg == 1) ? firstg : 0;

    // wave-cooperative disputed resolution (lane g = gt g; G == wave width)
    float4 gl = sbox[lane];
    unsigned long long dm = __ballot(fg > 1);
    while (dm) {
        int l = __ffsll((long long)dm) - 1;
        dm &= dm - 1;
        float4 pl;
        pl.x = __shfl(p.x, l, 64); pl.y = __shfl(p.y, l, 64);
        pl.z = __shfl(p.z, l, 64); pl.w = __shfl(p.w, l, 64);
        float iou = iou_clip(gl, pl);
        int g = lane;
        #pragma unroll
        for (int off = 32; off >= 1; off >>= 1) {
            float oi = __shfl_xor(iou, off, 64);
            int   og = __shfl_xor(g,   off, 64);
            if (oi > iou || (oi == iou && og < g)) { iou = oi; g = og; }
        }
        if (lane == l) tgt = g;   // first-occurrence argmax == jnp.argmax
    }

    if (!act) return;

    // epilogue: recompute am/iou at target (bit-identical helper path)
    float4 gbt = sbox[tgt];
    float vt  = in_box(ax, ay, gbt) * smask[tgt];
    float iout = iou_clip(gbt, p);
    float amt = align_metric_f(sqs, iout, vt);
    bool isfg = (fg != 0);
    float amv = isfg ? amt : 0.f;    // am * mask_pos (valid included)
    float iov = isfg ? iout : 0.f;   // overlaps * mask_pos (no valid mult)

    out_labels[o] = (float)slab[tgt];
    *(float4*)(out_bboxes + o * 4) = gbt;
    out_fg[o] = isfg ? 1.f : 0.f;
    ws_tgt[o] = tgt;
    ws_amv[o] = amv;

    if (isfg) {
        int gi = b * G + tgt;
        atomicMax(&pam[gi], __float_as_int(amv));  // vals>=0: int order == float order
        atomicMax(&pim[gi], __float_as_int(iov));
    }
}

// ---- Kernel 3: normalized target scores (pam/pim staged per-block). ----
__global__ __launch_bounds__(256) void k_scores(
    const int* __restrict__ ws_tgt, const float* __restrict__ ws_amv,
    const int* __restrict__ pam, const int* __restrict__ pim,
    const float* __restrict__ out_labels,
    float* __restrict__ out_scores,
    int B, int G, int NA)
{
    __shared__ int spam[64];
    __shared__ int spim[64];

    int b = blockIdx.y;
    int tid = threadIdx.x;
    if (tid < 64) {
        spam[tid] = pam[b * G + tid];
        spim[tid] = pim[b * G + tid];
    }
    __syncthreads();

    int a = blockIdx.x * blockDim.x + tid;
    if (a >= NA) return;
    size_t o = (size_t)b * NA + a;

    int tgt = ws_tgt[o];
    float amv = ws_amv[o];
    float pa = __int_as_float(spam[tgt]);
    float pi = __int_as_float(spim[tgt]);
    float wgt = amv / (pa + 1e-9f) * pi;
    float onehot = (out_labels[o] == 0.f) ? 1.f : 0.f;   // NC==1
    out_scores[o] = onehot * wgt;
}

extern "C" void kernel_launch(void* const* d_in, const int* in_sizes, int n_in,
                              void* d_out, int out_size, void* d_ws, size_t ws_size,
                              hipStream_t stream) {
    const float* pd_scores = (const float*)d_in[0];
    const float* pd_bboxes = (const float*)d_in[1];
    const float* anc       = (const float*)d_in[2];
    const int*   gt_labels = (const int*)d_in[3];
    const float* gt_bboxes = (const float*)d_in[4];
    const float* mask_gt   = (const float*)d_in[5];

    int NA = in_sizes[2] / 2;
    int B  = in_sizes[0] / NA;
    int G  = in_sizes[4] / (B * 4);

    float* out = (float*)d_out;
    float* out_labels = out;                               // (B,NA)
    float* out_bboxes = out_labels + (size_t)B * NA;       // (B,NA,4)
    float* out_scores = out_bboxes + (size_t)B * NA * 4;   // (B,NA,1)
    float* out_fg     = out_scores + (size_t)B * NA;       // (B,NA)

    int BG = B * G;
    int BNA = B * NA;
    float* thr    = (float*)d_ws;               // BG
    int*   pam    = (int*)(thr + BG);           // BG
    int*   pim    = pam + BG;                   // BG
    int*   ws_tgt = pim + BG;                   // BNA
    float* ws_amv = (float*)(ws_tgt + BNA);     // BNA

    k_thresh<<<dim3((BG + 3) / 4), dim3(256), 0, stream>>>(
        pd_scores, pd_bboxes, gt_bboxes, mask_gt, thr, pam, pim, B, G, NA);

    k_assign<<<dim3((NA + 255) / 256, B), dim3(256), 0, stream>>>(
        pd_scores, pd_bboxes, anc, gt_labels, gt_bboxes, mask_gt, thr,
        out_labels, out_bboxes, out_fg, ws_tgt, ws_amv, pam, pim, B, G, NA);

    k_scores<<<dim3((NA + 255) / 256, B), dim3(256), 0, stream>>>(
        ws_tgt, ws_amv, pam, pim, out_labels, out_scores, B, G, NA);
}

// Round 9
// 47.106 us; speedup vs baseline: 2.0725x; 1.0035x over previous
//
#include <hip/hip_runtime.h>

#define TOPK_K 13
#define KPAD 16
#define PCAP 384   // > max in-box anchors per gt (<=336 for 128px box)

// ---- shared math helpers: every am/IoU value in all kernels flows through
// these, so threshold comparisons and argmax are bit-exact vs each other. ----

__device__ __forceinline__ float iou_clip(const float4 g, const float4 p) {
    float ix1 = fmaxf(g.x, p.x), iy1 = fmaxf(g.y, p.y);
    float ix2 = fminf(g.z, p.z), iy2 = fminf(g.w, p.w);
    float iw = fmaxf(ix2 - ix1, 0.f);
    float ih = fmaxf(iy2 - iy1, 0.f);
    float inter = iw * ih;
    float a1 = (g.z - g.x) * (g.w - g.y);
    float a2 = (p.z - p.x) * (p.w - p.y);
    float iou = inter / (a1 + a2 - inter + 1e-7f);
    return fmaxf(iou, 0.f);
}

__device__ __forceinline__ float in_box(float ax, float ay, const float4 g) {
    float m = fminf(fminf(ax - g.x, ay - g.y), fminf(g.z - ax, g.w - ay));
    return (m > 0.f) ? 1.f : 0.f;
}

__device__ __forceinline__ float align_metric_f(float sqs, float iou, float valid) {
    float p2 = iou * iou;
    float p6 = p2 * p2 * p2;
    return sqs * p6 * valid;
}

// ---- Kernel 1: one wave per (b,g). Sets bit g of claim[b][a] for every
// anchor passing (in-box && am >= thr). Fast path: <13 positive metrics ->
// thr = 0 -> every in-box anchor passes (am >= 0 always). Rare path
// (npos >= 13): compute top-13 threshold, then clear bits where am < thr. ----
__global__ __launch_bounds__(256) void k_gt(
    const float* __restrict__ pd_scores, const float* __restrict__ pd_bboxes,
    const float* __restrict__ gt_bboxes, const float* __restrict__ mask_gt,
    unsigned long long* __restrict__ claim,
    int B, int G, int NA)
{
    __shared__ float plist[4][PCAP];
    __shared__ int   pcnt[4];

    int w4 = threadIdx.x >> 6;
    int lane = threadIdx.x & 63;
    int w = blockIdx.x * 4 + w4;
    if (w >= B * G) return;
    if (mask_gt[w] == 0.f) return;

    int b = w / G;
    int g = w - b * G;
    float4 gb = *(const float4*)(gt_bboxes + (size_t)w * 4);
    const float* ps = pd_scores + (size_t)b * NA;
    const float* pb = pd_bboxes + (size_t)b * NA * 4;
    unsigned long long* clb = claim + (size_t)b * NA;
    const unsigned long long gbit = 1ull << g;

    if (lane == 0) pcnt[w4] = 0;

    // analytic candidate rectangle per stride level (anchors form a grid)
    int rix0[3], riy0[3], rix1[3], riy1[3];
    #pragma unroll
    for (int lvl = 0; lvl < 3; ++lvl) {
        const int n = (lvl == 0) ? 80 : (lvl == 1 ? 40 : 20);
        const float sf = (float)(8 << lvl);
        rix0[lvl] = max(0,     (int)floorf(gb.x / sf - 0.5f));
        riy0[lvl] = max(0,     (int)floorf(gb.y / sf - 0.5f));
        rix1[lvl] = min(n - 1, (int)ceilf (gb.z / sf - 0.5f));
        riy1[lvl] = min(n - 1, (int)ceilf (gb.w / sf - 0.5f));
    }

    // single pass: set claim bits for all in-box anchors; collect positives
    #pragma unroll
    for (int lvl = 0; lvl < 3; ++lvl) {
        const int n   = (lvl == 0) ? 80 : (lvl == 1 ? 40 : 20);
        const int off = (lvl == 0) ? 0  : (lvl == 1 ? 6400 : 8000);
        const float sf = (float)(8 << lvl);
        int wdt = rix1[lvl] - rix0[lvl] + 1, hgt = riy1[lvl] - riy0[lvl] + 1;
        if (wdt <= 0 || hgt <= 0) continue;
        int n_c = wdt * hgt;
        for (int c = lane; c < n_c; c += 64) {
            int ix = rix0[lvl] + (c % wdt);
            int iy = riy0[lvl] + (c / wdt);
            float ax = (ix + 0.5f) * sf;   // exact f32 == reference anc
            float ay = (iy + 0.5f) * sf;
            if (in_box(ax, ay, gb) != 0.f) {
                int a = off + iy * n + ix;
                atomicOr(&clb[a], gbit);
                float4 p = *(const float4*)(pb + (size_t)a * 4);
                float iou = iou_clip(gb, p);
                float sqs = sqrtf(fmaxf(ps[a], 0.f));
                float am = align_metric_f(sqs, iou, 1.f);
                if (am > 0.f) {
                    int idx = atomicAdd(&pcnt[w4], 1);
                    if (idx < PCAP) plist[w4][idx] = am;
                }
            }
        }
    }

    if (pcnt[w4] < TOPK_K) return;   // thr == 0: claim bits already exact

    // ---- rare path: real top-13 threshold, then clear failing bits ----
    int n = pcnt[w4];
    float t[KPAD];
    #pragma unroll
    for (int i = 0; i < KPAD; ++i) t[i] = 0.f;
    for (int j = lane; j < n; j += 64) {
        float v = plist[w4][j];
        if (v > t[KPAD - 1]) {
            t[KPAD - 1] = v;
            #pragma unroll
            for (int i = KPAD - 1; i > 0; --i) {
                float hi = fmaxf(t[i - 1], t[i]);
                float lo = fminf(t[i - 1], t[i]);
                t[i - 1] = hi; t[i] = lo;
            }
        }
    }
    for (int off = 1; off < 64; off <<= 1) {
        float o[KPAD], m[KPAD];
        #pragma unroll
        for (int i = 0; i < KPAD; ++i) o[i] = __shfl_xor(t[i], off, 64);
        #pragma unroll
        for (int i = 0; i < KPAD; ++i) m[i] = fmaxf(t[i], o[KPAD - 1 - i]);
        #pragma unroll
        for (int s = 8; s >= 1; s >>= 1) {
            #pragma unroll
            for (int i = 0; i < KPAD; ++i) {
                if ((i & s) == 0) {
                    float hi = fmaxf(m[i], m[i + s]);
                    float lo = fminf(m[i], m[i + s]);
                    m[i] = hi; m[i + s] = lo;
                }
            }
        }
        #pragma unroll
        for (int i = 0; i < KPAD; ++i) t[i] = m[i];
    }
    float thr = t[TOPK_K - 1];

    // corrective pass: clear bit where am < thr (recompute am bit-identically)
    #pragma unroll
    for (int lvl = 0; lvl < 3; ++lvl) {
        const int n2  = (lvl == 0) ? 80 : (lvl == 1 ? 40 : 20);
        const int off = (lvl == 0) ? 0  : (lvl == 1 ? 6400 : 8000);
        const float sf = (float)(8 << lvl);
        int wdt = rix1[lvl] - rix0[lvl] + 1, hgt = riy1[lvl] - riy0[lvl] + 1;
        if (wdt <= 0 || hgt <= 0) continue;
        int n_c = wdt * hgt;
        for (int c = lane; c < n_c; c += 64) {
            int ix = rix0[lvl] + (c % wdt);
            int iy = riy0[lvl] + (c / wdt);
            float ax = (ix + 0.5f) * sf;
            float ay = (iy + 0.5f) * sf;
            if (in_box(ax, ay, gb) != 0.f) {
                int a = off + iy * n2 + ix;
                float4 p = *(const float4*)(pb + (size_t)a * 4);
                float iou = iou_clip(gb, p);
                float sqs = sqrtf(fmaxf(ps[a], 0.f));
                float am = align_metric_f(sqs, iou, 1.f);
                if (am < thr) atomicAnd(&clb[a], ~gbit);
            }
        }
    }
}

// ---- Kernel 2: per-(b,anchor). One 8B claim-word load -> popc/ffs;
// disputes resolved wave-cooperatively (lane g = gt g, G == wave width). ----
__global__ __launch_bounds__(256) void k_assign(
    const float* __restrict__ pd_scores, const float* __restrict__ pd_bboxes,
    const float* __restrict__ anc, const int* __restrict__ gt_labels,
    const float* __restrict__ gt_bboxes, const float* __restrict__ mask_gt,
    const unsigned long long* __restrict__ claim,
    float* __restrict__ out_labels, float* __restrict__ out_bboxes,
    float* __restrict__ out_fg,
    int* __restrict__ ws_tgt, float* __restrict__ ws_amv,
    int* __restrict__ pam, int* __restrict__ pim,
    int B, int G, int NA)
{
    __shared__ float4 sbox[64];
    __shared__ float  smask[64];
    __shared__ int    slab[64];

    int b = blockIdx.y;
    int tid = threadIdx.x;
    if (tid < 64) {
        sbox[tid]  = *(const float4*)(gt_bboxes + ((size_t)b * G + tid) * 4);
        smask[tid] = mask_gt[b * G + tid];
        int l = gt_labels[b * G + tid];
        slab[tid]  = (l < 0) ? 0 : l;
    }
    __syncthreads();

    int a = blockIdx.x * blockDim.x + tid;
    bool act = (a < NA);                 // no early return: all lanes serve shfl
    int lane = tid & 63;
    int ac = act ? a : (NA - 1);
    size_t o = (size_t)b * NA + ac;

    unsigned long long cw = act ? claim[o] : 0ull;
    float4 p = *(const float4*)(pd_bboxes + o * 4);

    int fg = (int)__popcll(cw);
    int tgt = (fg == 1) ? (__ffsll((long long)cw) - 1) : 0;

    // wave-cooperative disputed resolution
    float4 gl = sbox[lane];
    unsigned long long dm = __ballot(fg > 1);
    while (dm) {
        int l = __ffsll((long long)dm) - 1;
        dm &= dm - 1;
        float4 pl;
        pl.x = __shfl(p.x, l, 64); pl.y = __shfl(p.y, l, 64);
        pl.z = __shfl(p.z, l, 64); pl.w = __shfl(p.w, l, 64);
        float iou = iou_clip(gl, pl);
        int g = lane;
        #pragma unroll
        for (int off = 32; off >= 1; off >>= 1) {
            float oi = __shfl_xor(iou, off, 64);
            int   og = __shfl_xor(g,   off, 64);
            if (oi > iou || (oi == iou && og < g)) { iou = oi; g = og; }
        }
        if (lane == l) tgt = g;   // first-occurrence argmax == jnp.argmax
    }

    if (!act) return;

    // epilogue: recompute am/iou at target (bit-identical helper path)
    float4 gbt = sbox[tgt];
    float ax = anc[2 * ac], ay = anc[2 * ac + 1];
    float sqs = sqrtf(fmaxf(pd_scores[o], 0.f));
    float vt  = in_box(ax, ay, gbt) * smask[tgt];
    float iout = iou_clip(gbt, p);
    float amt = align_metric_f(sqs, iout, vt);
    bool isfg = (fg != 0);
    float amv = isfg ? amt : 0.f;    // am * mask_pos (valid included)
    float iov = isfg ? iout : 0.f;   // overlaps * mask_pos (no valid mult)

    out_labels[o] = (float)slab[tgt];
    *(float4*)(out_bboxes + o * 4) = gbt;
    out_fg[o] = isfg ? 1.f : 0.f;
    ws_tgt[o] = tgt;
    ws_amv[o] = amv;

    if (isfg) {
        int gi = b * G + tgt;
        atomicMax(&pam[gi], __float_as_int(amv));  // vals>=0: int order == float order
        atomicMax(&pim[gi], __float_as_int(iov));
    }
}

// ---- Kernel 3: normalized target scores (pam/pim staged per-block). ----
__global__ __launch_bounds__(256) void k_scores(
    const int* __restrict__ ws_tgt, const float* __restrict__ ws_amv,
    const int* __restrict__ pam, const int* __restrict__ pim,
    const float* __restrict__ out_labels,
    float* __restrict__ out_scores,
    int B, int G, int NA)
{
    __shared__ int spam[64];
    __shared__ int spim[64];

    int b = blockIdx.y;
    int tid = threadIdx.x;
    if (tid < 64) {
        spam[tid] = pam[b * G + tid];
        spim[tid] = pim[b * G + tid];
    }
    __syncthreads();

    int a = blockIdx.x * blockDim.x + tid;
    if (a >= NA) return;
    size_t o = (size_t)b * NA + a;

    int tgt = ws_tgt[o];
    float amv = ws_amv[o];
    float pa = __int_as_float(spam[tgt]);
    float pi = __int_as_float(spim[tgt]);
    float wgt = amv / (pa + 1e-9f) * pi;
    float onehot = (out_labels[o] == 0.f) ? 1.f : 0.f;   // NC==1
    out_scores[o] = onehot * wgt;
}

extern "C" void kernel_launch(void* const* d_in, const int* in_sizes, int n_in,
                              void* d_out, int out_size, void* d_ws, size_t ws_size,
                              hipStream_t stream) {
    const float* pd_scores = (const float*)d_in[0];
    const float* pd_bboxes = (const float*)d_in[1];
    const float* anc       = (const float*)d_in[2];
    const int*   gt_labels = (const int*)d_in[3];
    const float* gt_bboxes = (const float*)d_in[4];
    const float* mask_gt   = (const float*)d_in[5];

    int NA = in_sizes[2] / 2;
    int B  = in_sizes[0] / NA;
    int G  = in_sizes[4] / (B * 4);

    float* out = (float*)d_out;
    float* out_labels = out;                               // (B,NA)
    float* out_bboxes = out_labels + (size_t)B * NA;       // (B,NA,4)
    float* out_scores = out_bboxes + (size_t)B * NA * 4;   // (B,NA,1)
    float* out_fg     = out_scores + (size_t)B * NA;       // (B,NA)

    int BG = B * G;
    int BNA = B * NA;
    unsigned long long* claim = (unsigned long long*)d_ws;  // BNA (8B each)
    int*   pam    = (int*)(claim + BNA);        // BG
    int*   pim    = pam + BG;                   // BG
    int*   ws_tgt = pim + BG;                   // BNA
    float* ws_amv = (float*)(ws_tgt + BNA);     // BNA

    // zero claim+pam+pim in one contiguous memset node
    hipMemsetAsync(claim, 0, (size_t)BNA * 8 + (size_t)BG * 8, stream);

    k_gt<<<dim3((BG + 3) / 4), dim3(256), 0, stream>>>(
        pd_scores, pd_bboxes, gt_bboxes, mask_gt, claim, B, G, NA);

    k_assign<<<dim3((NA + 255) / 256, B), dim3(256), 0, stream>>>(
        pd_scores, pd_bboxes, anc, gt_labels, gt_bboxes, mask_gt, claim,
        out_labels, out_bboxes, out_fg, ws_tgt, ws_amv, pam, pim, B, G, NA);

    k_scores<<<dim3((NA + 255) / 256, B), dim3(256), 0, stream>>>(
        ws_tgt, ws_amv, pam, pim, out_labels, out_scores, B, G, NA);
}